// Round 7
// baseline (122.908 us; speedup 1.0000x reference)
//
#include <hip/hip_runtime.h>
#include <stdint.h>

// HammingDistance via bit-plane packing.
// Codes 0..7 = 3 bits. Pack bit-plane b of 32 consecutive d's into one u32.
// mismatch(32 elems) = popc((x0^y0)|(x1^y1)|(x2^y2))
// out[n,m] = total_mismatch / 256 (exact, pow2).
//
// R7: 256x128 block tile, 16x8 per-thread micro-tile (was 128x128 / 8x8).
// Cuts LDS reads/output 25%, halves per-output loop overhead and block count.
// cnt stays u16-packed (64 regs). asm accumulate reverted (R6 null).
// As slot = g ^ (row>>4)  (tm spread), Bs slot = g ^ (row>>3)  (tn 2-way).

#define D_    256
#define GRP   8          // 32-element groups per row
#define RWORD 32         // padded u32 per packed row (8 groups * 4)
#define BM    256
#define BN    128

__global__ __launch_bounds__(256) void pack_planes_kernel(
    const float* __restrict__ in, uint32_t* __restrict__ out, int total)
{
    int idx = blockIdx.x * blockDim.x + threadIdx.x;   // one (row, group) each
    if (idx >= total) return;
    int row = idx >> 3, g = idx & 7;
    const float* p = in + (size_t)row * D_ + g * 32;
    uint32_t b0 = 0, b1 = 0, b2 = 0;
#pragma unroll
    for (int d = 0; d < 32; d += 4) {
        float4 f = *(const float4*)(p + d);
        uint32_t c0 = (uint32_t)f.x, c1 = (uint32_t)f.y;
        uint32_t c2 = (uint32_t)f.z, c3 = (uint32_t)f.w;
        b0 |= ((c0 & 1) << d) | ((c1 & 1) << (d + 1)) |
              ((c2 & 1) << (d + 2)) | ((c3 & 1) << (d + 3));
        b1 |= (((c0 >> 1) & 1) << d) | (((c1 >> 1) & 1) << (d + 1)) |
              (((c2 >> 1) & 1) << (d + 2)) | (((c3 >> 1) & 1) << (d + 3));
        b2 |= (((c0 >> 2) & 1) << d) | (((c1 >> 2) & 1) << (d + 1)) |
              (((c2 >> 2) & 1) << (d + 2)) | (((c3 >> 2) & 1) << (d + 3));
    }
    uint4 v; v.x = b0; v.y = b1; v.z = b2; v.w = 0;
    *(uint4*)&out[(size_t)row * RWORD + g * 4] = v;
}

__global__ __launch_bounds__(256) void hamming_planes_kernel(
    const uint32_t* __restrict__ Xp, const uint32_t* __restrict__ Yp,
    float* __restrict__ out, int Mcols)
{
    __shared__ __align__(16) uint4 As4[BM * GRP];   // 32 KB
    __shared__ __align__(16) uint4 Bs4[BN * GRP];   // 16 KB

    const int tid = threadIdx.x;
    const int tn = tid & 15;          // 16 col-threads  (8 cols each)
    const int tm = tid >> 4;          // 16 row-threads  (16 rows each)
    const int rowBase = blockIdx.y * BM;
    const int colBase = blockIdx.x * BN;

    // ---- load phase: lane-contiguous, swizzled writes ----
    const uint4* Xg = (const uint4*)(Xp + (size_t)rowBase * RWORD);
    const uint4* Yg = (const uint4*)(Yp + (size_t)colBase * RWORD);
#pragma unroll
    for (int i = 0; i < 8; ++i) {                   // As: 2048 uint4
        int f = i * 256 + tid;
        int row = f >> 3, g = f & 7;
        As4[row * 8 + ((g ^ (row >> 4)) & 7)] = Xg[f];
    }
#pragma unroll
    for (int i = 0; i < 4; ++i) {                   // Bs: 1024 uint4
        int f = i * 256 + tid;
        int row = f >> 3, g = f & 7;
        Bs4[row * 8 + ((g ^ (row >> 3)) & 7)] = Yg[f];
    }
    __syncthreads();

    // cnt[i][jp]: low16 = column 2*jp, high16 = column 2*jp+1
    uint32_t cnt[16][4] = {};

#pragma unroll 1
    for (int g = 0; g < GRP; ++g) {
        const uint4* aP = As4 + tm * 16 * 8 + ((g ^ tm) & 7);   // rows tm*16..
        const uint4* bP = Bs4 + tn * 8 * 8 + ((g ^ tn) & 7);    // cols tn*8..
        uint4 b[8];
#pragma unroll
        for (int j = 0; j < 8; ++j) b[j] = bP[j * 8];
#pragma unroll
        for (int i = 0; i < 16; ++i) {
            uint4 a = aP[i * 8];
#pragma unroll
            for (int jp = 0; jp < 4; ++jp) {
                uint32_t ue = (a.x ^ b[2 * jp].x) | (a.y ^ b[2 * jp].y) |
                              (a.z ^ b[2 * jp].z);
                uint32_t uo = (a.x ^ b[2 * jp + 1].x) | (a.y ^ b[2 * jp + 1].y) |
                              (a.z ^ b[2 * jp + 1].z);
                cnt[i][jp] += __popc(ue) + (__popc(uo) << 16);
            }
        }
    }

    const float inv = 1.0f / (float)D_;     // out = mismatches / 256
#pragma unroll
    for (int i = 0; i < 16; ++i) {
        float* orow = &out[(size_t)(rowBase + tm * 16 + i) * Mcols + colBase + tn * 8];
        float4 r0, r1;
        r0.x = (float)(cnt[i][0] & 0xffffu) * inv;
        r0.y = (float)(cnt[i][0] >> 16) * inv;
        r0.z = (float)(cnt[i][1] & 0xffffu) * inv;
        r0.w = (float)(cnt[i][1] >> 16) * inv;
        r1.x = (float)(cnt[i][2] & 0xffffu) * inv;
        r1.y = (float)(cnt[i][2] >> 16) * inv;
        r1.z = (float)(cnt[i][3] & 0xffffu) * inv;
        r1.w = (float)(cnt[i][3] >> 16) * inv;
        *(float4*)(orow + 0) = r0;
        *(float4*)(orow + 4) = r1;
    }
}

// ---------------- fallback (ws too small): fused one-hot kernel ----------------
__device__ __forceinline__ uint32_t pack4_oh(const float* p) {
    float4 f = *(const float4*)p;
    return (1u << (int)f.x) | ((1u << (int)f.y) << 8) |
           ((1u << (int)f.z) << 16) | ((1u << (int)f.w) << 24);
}

__global__ __launch_bounds__(256) void hamming_fallback_kernel(
    const float* __restrict__ X, const float* __restrict__ Y,
    float* __restrict__ out, int Mcols)
{
    __shared__ uint32_t As[16][64];
    __shared__ uint32_t Bs[16][64];
    const int tid = threadIdx.x;
    const int tn = tid & 15, tm = tid >> 4;
    const int rowBase = blockIdx.y * 64, colBase = blockIdx.x * 64;
    const int lrow = tid >> 2, lw4 = (tid & 3) * 4;
    uint32_t cnt[4][4] = {};
    for (int k0 = 0; k0 < 64; k0 += 16) {
        uint4 av, bv;
        const float* px = X + (size_t)(rowBase + lrow) * D_ + (size_t)(k0 + lw4) * 4;
        const float* py = Y + (size_t)(colBase + lrow) * D_ + (size_t)(k0 + lw4) * 4;
        av.x = pack4_oh(px + 0);  av.y = pack4_oh(px + 4);
        av.z = pack4_oh(px + 8);  av.w = pack4_oh(px + 12);
        bv.x = pack4_oh(py + 0);  bv.y = pack4_oh(py + 4);
        bv.z = pack4_oh(py + 8);  bv.w = pack4_oh(py + 12);
        __syncthreads();
        As[lw4 + 0][lrow] = av.x;  As[lw4 + 1][lrow] = av.y;
        As[lw4 + 2][lrow] = av.z;  As[lw4 + 3][lrow] = av.w;
        Bs[lw4 + 0][lrow] = bv.x;  Bs[lw4 + 1][lrow] = bv.y;
        Bs[lw4 + 2][lrow] = bv.z;  Bs[lw4 + 3][lrow] = bv.w;
        __syncthreads();
#pragma unroll
        for (int k = 0; k < 16; ++k) {
            uint4 a4 = *(const uint4*)&As[k][tm * 4];
            uint4 b4 = *(const uint4*)&Bs[k][tn * 4];
            uint32_t a[4] = {a4.x, a4.y, a4.z, a4.w};
            uint32_t b[4] = {b4.x, b4.y, b4.z, b4.w};
#pragma unroll
            for (int i = 0; i < 4; ++i)
#pragma unroll
                for (int j = 0; j < 4; ++j)
                    cnt[i][j] += __popc(a[i] & b[j]);
        }
    }
    const float inv = 1.0f / (float)D_;
#pragma unroll
    for (int i = 0; i < 4; ++i) {
        float4 r;
        r.x = 1.0f - (float)cnt[i][0] * inv;
        r.y = 1.0f - (float)cnt[i][1] * inv;
        r.z = 1.0f - (float)cnt[i][2] * inv;
        r.w = 1.0f - (float)cnt[i][3] * inv;
        *(float4*)&out[(size_t)(rowBase + tm * 4 + i) * Mcols + colBase + tn * 4] = r;
    }
}

extern "C" void kernel_launch(void* const* d_in, const int* in_sizes, int n_in,
                              void* d_out, int out_size, void* d_ws, size_t ws_size,
                              hipStream_t stream) {
    const float* x = (const float*)d_in[0];
    const float* y = (const float*)d_in[1];
    float* out = (float*)d_out;
    const int N = in_sizes[0] / D_;
    const int M = in_sizes[1] / D_;

    const size_t need = ((size_t)N + (size_t)M) * RWORD * sizeof(uint32_t);
    if (ws_size >= need) {
        uint32_t* Xp = (uint32_t*)d_ws;
        uint32_t* Yp = Xp + (size_t)N * RWORD;
        int xt = N * GRP, yt = M * GRP;
        pack_planes_kernel<<<(xt + 255) / 256, 256, 0, stream>>>(x, Xp, xt);
        pack_planes_kernel<<<(yt + 255) / 256, 256, 0, stream>>>(y, Yp, yt);
        dim3 grid(M / BN, N / BM);
        hamming_planes_kernel<<<grid, 256, 0, stream>>>(Xp, Yp, out, M);
    } else {
        dim3 grid(M / 64, N / 64);
        hamming_fallback_kernel<<<grid, 256, 0, stream>>>(x, y, out, M);
    }
}

// Round 8
// 115.404 us; speedup vs baseline: 1.0650x; 1.0650x over previous
//
#include <hip/hip_runtime.h>
#include <stdint.h>

// HammingDistance via bit-plane packing.
// Codes 0..7 = 3 bits. Pack bit-plane b of 32 consecutive d's into one u32.
// mismatch(32 elems) = popc((x0^y0)|(x1^y1)|(x2^y2))
// out[n,m] = total_mismatch / 256 (exact, pow2).
//
// R8: revert to R5 128x128/8x8 (R7's 256x128 crossed the 128-VGPR occupancy
// step). Add explicit software double-buffer for b across g (named bA/bB,
// static indexing) so each g's 8 ds_read_b128 issue during the previous g's
// compute instead of serializing at the unroll-1 loop boundary.

#define D_    256
#define GRP   8          // 32-element groups per row
#define RWORD 32         // padded u32 per packed row (8 groups * 4)
#define BM    128
#define BN    128

__global__ __launch_bounds__(256) void pack_planes_kernel(
    const float* __restrict__ in, uint32_t* __restrict__ out, int total)
{
    int idx = blockIdx.x * blockDim.x + threadIdx.x;   // one (row, group) each
    if (idx >= total) return;
    int row = idx >> 3, g = idx & 7;
    const float* p = in + (size_t)row * D_ + g * 32;
    uint32_t b0 = 0, b1 = 0, b2 = 0;
#pragma unroll
    for (int d = 0; d < 32; d += 4) {
        float4 f = *(const float4*)(p + d);
        uint32_t c0 = (uint32_t)f.x, c1 = (uint32_t)f.y;
        uint32_t c2 = (uint32_t)f.z, c3 = (uint32_t)f.w;
        b0 |= ((c0 & 1) << d) | ((c1 & 1) << (d + 1)) |
              ((c2 & 1) << (d + 2)) | ((c3 & 1) << (d + 3));
        b1 |= (((c0 >> 1) & 1) << d) | (((c1 >> 1) & 1) << (d + 1)) |
              (((c2 >> 1) & 1) << (d + 2)) | (((c3 >> 1) & 1) << (d + 3));
        b2 |= (((c0 >> 2) & 1) << d) | (((c1 >> 2) & 1) << (d + 1)) |
              (((c2 >> 2) & 1) << (d + 2)) | (((c3 >> 2) & 1) << (d + 3));
    }
    uint4 v; v.x = b0; v.y = b1; v.z = b2; v.w = 0;
    *(uint4*)&out[(size_t)row * RWORD + g * 4] = v;
}

// accumulate one (a, b-even, b-odd) pair into packed-u16 cnt
#define ACC_PAIR(cntw, av, be, bo)                                          \
    do {                                                                    \
        uint32_t ue_ = ((av).x ^ (be).x) | ((av).y ^ (be).y) |              \
                       ((av).z ^ (be).z);                                   \
        uint32_t uo_ = ((av).x ^ (bo).x) | ((av).y ^ (bo).y) |              \
                       ((av).z ^ (bo).z);                                   \
        (cntw) += __popc(ue_) + (__popc(uo_) << 16);                        \
    } while (0)

__global__ __launch_bounds__(256) void hamming_planes_kernel(
    const uint32_t* __restrict__ Xp, const uint32_t* __restrict__ Yp,
    float* __restrict__ out, int Mcols)
{
    // slot = g ^ ((row>>3)&7): b-reads land 2-way (free), a-reads spread.
    __shared__ __align__(16) uint4 As4[BM * GRP];
    __shared__ __align__(16) uint4 Bs4[BN * GRP];

    const int tid = threadIdx.x;
    const int tn = tid & 15;          // 16 col-threads
    const int tm = tid >> 4;          // 16 row-threads
    const int rowBase = blockIdx.y * BM;
    const int colBase = blockIdx.x * BN;

    // ---- load phase: 1024 uint4 per array, 4 per thread, lane-contiguous ----
    const uint4* Xg = (const uint4*)(Xp + (size_t)rowBase * RWORD);
    const uint4* Yg = (const uint4*)(Yp + (size_t)colBase * RWORD);
#pragma unroll
    for (int i = 0; i < 4; ++i) {
        int f = i * 256 + tid;               // flat (row*8 + g)
        int swz = (f & ~7) | ((f & 7) ^ ((f >> 6) & 7));
        As4[swz] = Xg[f];
        Bs4[swz] = Yg[f];
    }
    __syncthreads();

    // cnt[i][jp]: low16 = column 2*jp, high16 = column 2*jp+1
    uint32_t cnt[8][4] = {};

    const uint4* aBase = As4 + tm * 64;   // rows tm*8..tm*8+7
    const uint4* bBase = Bs4 + tn * 64;   // cols tn*8..tn*8+7

    uint4 bA[8], bB[8];
#pragma unroll
    for (int j = 0; j < 8; ++j) bA[j] = bBase[j * 8 + (tn & 7)];  // g=0

#pragma unroll 1
    for (int gp = 0; gp < 4; ++gp) {
        const int g0 = 2 * gp, g1 = 2 * gp + 1, g2 = (2 * gp + 2) & 7;
        const int sa0 = (g0 ^ tm) & 7, sa1 = (g1 ^ tm) & 7;
        const int sb1 = (g1 ^ tn) & 7, sb2 = (g2 ^ tn) & 7;

        // prefetch odd-g b while computing even-g
#pragma unroll
        for (int j = 0; j < 8; ++j) bB[j] = bBase[j * 8 + sb1];
#pragma unroll
        for (int i = 0; i < 8; ++i) {
            uint4 a = aBase[i * 8 + sa0];
#pragma unroll
            for (int jp = 0; jp < 4; ++jp)
                ACC_PAIR(cnt[i][jp], a, bA[2 * jp], bA[2 * jp + 1]);
        }

        // prefetch next even-g b (wraps harmlessly on last iter)
#pragma unroll
        for (int j = 0; j < 8; ++j) bA[j] = bBase[j * 8 + sb2];
#pragma unroll
        for (int i = 0; i < 8; ++i) {
            uint4 a = aBase[i * 8 + sa1];
#pragma unroll
            for (int jp = 0; jp < 4; ++jp)
                ACC_PAIR(cnt[i][jp], a, bB[2 * jp], bB[2 * jp + 1]);
        }
    }

    const float inv = 1.0f / (float)D_;     // out = mismatches / 256
#pragma unroll
    for (int i = 0; i < 8; ++i) {
        float* orow = &out[(size_t)(rowBase + tm * 8 + i) * Mcols + colBase + tn * 8];
        float4 r0, r1;
        r0.x = (float)(cnt[i][0] & 0xffffu) * inv;
        r0.y = (float)(cnt[i][0] >> 16) * inv;
        r0.z = (float)(cnt[i][1] & 0xffffu) * inv;
        r0.w = (float)(cnt[i][1] >> 16) * inv;
        r1.x = (float)(cnt[i][2] & 0xffffu) * inv;
        r1.y = (float)(cnt[i][2] >> 16) * inv;
        r1.z = (float)(cnt[i][3] & 0xffffu) * inv;
        r1.w = (float)(cnt[i][3] >> 16) * inv;
        *(float4*)(orow + 0) = r0;
        *(float4*)(orow + 4) = r1;
    }
}

// ---------------- fallback (ws too small): fused one-hot kernel ----------------
__device__ __forceinline__ uint32_t pack4_oh(const float* p) {
    float4 f = *(const float4*)p;
    return (1u << (int)f.x) | ((1u << (int)f.y) << 8) |
           ((1u << (int)f.z) << 16) | ((1u << (int)f.w) << 24);
}

__global__ __launch_bounds__(256) void hamming_fallback_kernel(
    const float* __restrict__ X, const float* __restrict__ Y,
    float* __restrict__ out, int Mcols)
{
    __shared__ uint32_t As[16][64];
    __shared__ uint32_t Bs[16][64];
    const int tid = threadIdx.x;
    const int tn = tid & 15, tm = tid >> 4;
    const int rowBase = blockIdx.y * 64, colBase = blockIdx.x * 64;
    const int lrow = tid >> 2, lw4 = (tid & 3) * 4;
    uint32_t cnt[4][4] = {};
    for (int k0 = 0; k0 < 64; k0 += 16) {
        uint4 av, bv;
        const float* px = X + (size_t)(rowBase + lrow) * D_ + (size_t)(k0 + lw4) * 4;
        const float* py = Y + (size_t)(colBase + lrow) * D_ + (size_t)(k0 + lw4) * 4;
        av.x = pack4_oh(px + 0);  av.y = pack4_oh(px + 4);
        av.z = pack4_oh(px + 8);  av.w = pack4_oh(px + 12);
        bv.x = pack4_oh(py + 0);  bv.y = pack4_oh(py + 4);
        bv.z = pack4_oh(py + 8);  bv.w = pack4_oh(py + 12);
        __syncthreads();
        As[lw4 + 0][lrow] = av.x;  As[lw4 + 1][lrow] = av.y;
        As[lw4 + 2][lrow] = av.z;  As[lw4 + 3][lrow] = av.w;
        Bs[lw4 + 0][lrow] = bv.x;  Bs[lw4 + 1][lrow] = bv.y;
        Bs[lw4 + 2][lrow] = bv.z;  Bs[lw4 + 3][lrow] = bv.w;
        __syncthreads();
#pragma unroll
        for (int k = 0; k < 16; ++k) {
            uint4 a4 = *(const uint4*)&As[k][tm * 4];
            uint4 b4 = *(const uint4*)&Bs[k][tn * 4];
            uint32_t a[4] = {a4.x, a4.y, a4.z, a4.w};
            uint32_t b[4] = {b4.x, b4.y, b4.z, b4.w};
#pragma unroll
            for (int i = 0; i < 4; ++i)
#pragma unroll
                for (int j = 0; j < 4; ++j)
                    cnt[i][j] += __popc(a[i] & b[j]);
        }
    }
    const float inv = 1.0f / (float)D_;
#pragma unroll
    for (int i = 0; i < 4; ++i) {
        float4 r;
        r.x = 1.0f - (float)cnt[i][0] * inv;
        r.y = 1.0f - (float)cnt[i][1] * inv;
        r.z = 1.0f - (float)cnt[i][2] * inv;
        r.w = 1.0f - (float)cnt[i][3] * inv;
        *(float4*)&out[(size_t)(rowBase + tm * 4 + i) * Mcols + colBase + tn * 4] = r;
    }
}

extern "C" void kernel_launch(void* const* d_in, const int* in_sizes, int n_in,
                              void* d_out, int out_size, void* d_ws, size_t ws_size,
                              hipStream_t stream) {
    const float* x = (const float*)d_in[0];
    const float* y = (const float*)d_in[1];
    float* out = (float*)d_out;
    const int N = in_sizes[0] / D_;
    const int M = in_sizes[1] / D_;

    const size_t need = ((size_t)N + (size_t)M) * RWORD * sizeof(uint32_t);
    if (ws_size >= need) {
        uint32_t* Xp = (uint32_t*)d_ws;
        uint32_t* Yp = Xp + (size_t)N * RWORD;
        int xt = N * GRP, yt = M * GRP;
        pack_planes_kernel<<<(xt + 255) / 256, 256, 0, stream>>>(x, Xp, xt);
        pack_planes_kernel<<<(yt + 255) / 256, 256, 0, stream>>>(y, Yp, yt);
        dim3 grid(M / BN, N / BM);
        hamming_planes_kernel<<<grid, 256, 0, stream>>>(Xp, Yp, out, M);
    } else {
        dim3 grid(M / 64, N / 64);
        hamming_fallback_kernel<<<grid, 256, 0, stream>>>(x, y, out, M);
    }
}

// Round 9
// 110.669 us; speedup vs baseline: 1.1106x; 1.0428x over previous
//
#include <hip/hip_runtime.h>
#include <stdint.h>

// HammingDistance via bit-plane packing.
// Codes 0..7 = 3 bits. Pack bit-plane b of 32 consecutive d's into one u32.
// mismatch(32 elems) = popc((x0^y0)|(x1^y1)|(x2^y2))
// out[n,m] = total_mismatch / 256 (exact, pow2).
//
// R9 = R5 structure (best, 104us) with ONE change: LDS fragment reads are
// 12B vec3 (ds_read_b96) instead of 16B uint4 -- the stored .w pad word is
// dead, so b128 reads waste 25% of LDS bytes. Slots stay 16B-aligned and
// 16B-strided (writes unchanged); only reads shrink. Also drops b[] storage
// from 32 to 24 VGPRs (pressure strictly down).

#define D_    256
#define GRP   8          // 32-element groups per row
#define RWORD 32         // padded u32 per packed row (8 groups * 4)
#define BM    128
#define BN    128

typedef unsigned int u32x3 __attribute__((ext_vector_type(3)));  // sizeof 16

__global__ __launch_bounds__(256) void pack_planes_kernel(
    const float* __restrict__ in, uint32_t* __restrict__ out, int total)
{
    int idx = blockIdx.x * blockDim.x + threadIdx.x;   // one (row, group) each
    if (idx >= total) return;
    int row = idx >> 3, g = idx & 7;
    const float* p = in + (size_t)row * D_ + g * 32;
    uint32_t b0 = 0, b1 = 0, b2 = 0;
#pragma unroll
    for (int d = 0; d < 32; d += 4) {
        float4 f = *(const float4*)(p + d);
        uint32_t c0 = (uint32_t)f.x, c1 = (uint32_t)f.y;
        uint32_t c2 = (uint32_t)f.z, c3 = (uint32_t)f.w;
        b0 |= ((c0 & 1) << d) | ((c1 & 1) << (d + 1)) |
              ((c2 & 1) << (d + 2)) | ((c3 & 1) << (d + 3));
        b1 |= (((c0 >> 1) & 1) << d) | (((c1 >> 1) & 1) << (d + 1)) |
              (((c2 >> 1) & 1) << (d + 2)) | (((c3 >> 1) & 1) << (d + 3));
        b2 |= (((c0 >> 2) & 1) << d) | (((c1 >> 2) & 1) << (d + 1)) |
              (((c2 >> 2) & 1) << (d + 2)) | (((c3 >> 2) & 1) << (d + 3));
    }
    uint4 v; v.x = b0; v.y = b1; v.z = b2; v.w = 0;
    *(uint4*)&out[(size_t)row * RWORD + g * 4] = v;
}

__global__ __launch_bounds__(256) void hamming_planes_kernel(
    const uint32_t* __restrict__ Xp, const uint32_t* __restrict__ Yp,
    float* __restrict__ out, int Mcols)
{
    // slot = g ^ ((row>>3)&7): b-reads land 2-way, a-reads broadcast/spread.
    __shared__ __align__(16) uint4 As4[BM * GRP];
    __shared__ __align__(16) uint4 Bs4[BN * GRP];

    const int tid = threadIdx.x;
    const int tn = tid & 15;          // 16 col-threads
    const int tm = tid >> 4;          // 16 row-threads
    const int rowBase = blockIdx.y * BM;
    const int colBase = blockIdx.x * BN;

    // ---- load phase: 1024 uint4 per array, 4 per thread, lane-contiguous ----
    const uint4* Xg = (const uint4*)(Xp + (size_t)rowBase * RWORD);
    const uint4* Yg = (const uint4*)(Yp + (size_t)colBase * RWORD);
#pragma unroll
    for (int i = 0; i < 4; ++i) {
        int f = i * 256 + tid;               // flat (row*8 + g)
        int swz = (f & ~7) | ((f & 7) ^ ((f >> 6) & 7));
        As4[swz] = Xg[f];
        Bs4[swz] = Yg[f];
    }
    __syncthreads();

    // cnt[i][jp]: low16 = column 2*jp, high16 = column 2*jp+1
    uint32_t cnt[8][4] = {};

    // 12B vec3 views of the 16B-strided slot arrays (reads skip the pad word)
    const u32x3* aBase = (const u32x3*)(As4 + tm * 64);   // rows tm*8..tm*8+7
    const u32x3* bBase = (const u32x3*)(Bs4 + tn * 64);   // cols tn*8..tn*8+7

#pragma unroll 1
    for (int g = 0; g < GRP; ++g) {
        const int sa = (g ^ tm) & 7;
        const int sb = (g ^ tn) & 7;
        u32x3 b[8];
#pragma unroll
        for (int j = 0; j < 8; ++j) b[j] = bBase[j * 8 + sb];
#pragma unroll
        for (int i = 0; i < 8; ++i) {
            u32x3 a = aBase[i * 8 + sa];
#pragma unroll
            for (int jp = 0; jp < 4; ++jp) {
                uint32_t ue = (a.x ^ b[2 * jp].x) | (a.y ^ b[2 * jp].y) |
                              (a.z ^ b[2 * jp].z);
                uint32_t uo = (a.x ^ b[2 * jp + 1].x) | (a.y ^ b[2 * jp + 1].y) |
                              (a.z ^ b[2 * jp + 1].z);
                cnt[i][jp] += __popc(ue) + (__popc(uo) << 16);
            }
        }
    }

    const float inv = 1.0f / (float)D_;     // out = mismatches / 256
#pragma unroll
    for (int i = 0; i < 8; ++i) {
        float* orow = &out[(size_t)(rowBase + tm * 8 + i) * Mcols + colBase + tn * 8];
        float4 r0, r1;
        r0.x = (float)(cnt[i][0] & 0xffffu) * inv;
        r0.y = (float)(cnt[i][0] >> 16) * inv;
        r0.z = (float)(cnt[i][1] & 0xffffu) * inv;
        r0.w = (float)(cnt[i][1] >> 16) * inv;
        r1.x = (float)(cnt[i][2] & 0xffffu) * inv;
        r1.y = (float)(cnt[i][2] >> 16) * inv;
        r1.z = (float)(cnt[i][3] & 0xffffu) * inv;
        r1.w = (float)(cnt[i][3] >> 16) * inv;
        *(float4*)(orow + 0) = r0;
        *(float4*)(orow + 4) = r1;
    }
}

// ---------------- fallback (ws too small): fused one-hot kernel ----------------
__device__ __forceinline__ uint32_t pack4_oh(const float* p) {
    float4 f = *(const float4*)p;
    return (1u << (int)f.x) | ((1u << (int)f.y) << 8) |
           ((1u << (int)f.z) << 16) | ((1u << (int)f.w) << 24);
}

__global__ __launch_bounds__(256) void hamming_fallback_kernel(
    const float* __restrict__ X, const float* __restrict__ Y,
    float* __restrict__ out, int Mcols)
{
    __shared__ uint32_t As[16][64];
    __shared__ uint32_t Bs[16][64];
    const int tid = threadIdx.x;
    const int tn = tid & 15, tm = tid >> 4;
    const int rowBase = blockIdx.y * 64, colBase = blockIdx.x * 64;
    const int lrow = tid >> 2, lw4 = (tid & 3) * 4;
    uint32_t cnt[4][4] = {};
    for (int k0 = 0; k0 < 64; k0 += 16) {
        uint4 av, bv;
        const float* px = X + (size_t)(rowBase + lrow) * D_ + (size_t)(k0 + lw4) * 4;
        const float* py = Y + (size_t)(colBase + lrow) * D_ + (size_t)(k0 + lw4) * 4;
        av.x = pack4_oh(px + 0);  av.y = pack4_oh(px + 4);
        av.z = pack4_oh(px + 8);  av.w = pack4_oh(px + 12);
        bv.x = pack4_oh(py + 0);  bv.y = pack4_oh(py + 4);
        bv.z = pack4_oh(py + 8);  bv.w = pack4_oh(py + 12);
        __syncthreads();
        As[lw4 + 0][lrow] = av.x;  As[lw4 + 1][lrow] = av.y;
        As[lw4 + 2][lrow] = av.z;  As[lw4 + 3][lrow] = av.w;
        Bs[lw4 + 0][lrow] = bv.x;  Bs[lw4 + 1][lrow] = bv.y;
        Bs[lw4 + 2][lrow] = bv.z;  Bs[lw4 + 3][lrow] = bv.w;
        __syncthreads();
#pragma unroll
        for (int k = 0; k < 16; ++k) {
            uint4 a4 = *(const uint4*)&As[k][tm * 4];
            uint4 b4 = *(const uint4*)&Bs[k][tn * 4];
            uint32_t a[4] = {a4.x, a4.y, a4.z, a4.w};
            uint32_t b[4] = {b4.x, b4.y, b4.z, b4.w};
#pragma unroll
            for (int i = 0; i < 4; ++i)
#pragma unroll
                for (int j = 0; j < 4; ++j)
                    cnt[i][j] += __popc(a[i] & b[j]);
        }
    }
    const float inv = 1.0f / (float)D_;
#pragma unroll
    for (int i = 0; i < 4; ++i) {
        float4 r;
        r.x = 1.0f - (float)cnt[i][0] * inv;
        r.y = 1.0f - (float)cnt[i][1] * inv;
        r.z = 1.0f - (float)cnt[i][2] * inv;
        r.w = 1.0f - (float)cnt[i][3] * inv;
        *(float4*)&out[(size_t)(rowBase + tm * 4 + i) * Mcols + colBase + tn * 4] = r;
    }
}

extern "C" void kernel_launch(void* const* d_in, const int* in_sizes, int n_in,
                              void* d_out, int out_size, void* d_ws, size_t ws_size,
                              hipStream_t stream) {
    const float* x = (const float*)d_in[0];
    const float* y = (const float*)d_in[1];
    float* out = (float*)d_out;
    const int N = in_sizes[0] / D_;
    const int M = in_sizes[1] / D_;

    const size_t need = ((size_t)N + (size_t)M) * RWORD * sizeof(uint32_t);
    if (ws_size >= need) {
        uint32_t* Xp = (uint32_t*)d_ws;
        uint32_t* Yp = Xp + (size_t)N * RWORD;
        int xt = N * GRP, yt = M * GRP;
        pack_planes_kernel<<<(xt + 255) / 256, 256, 0, stream>>>(x, Xp, xt);
        pack_planes_kernel<<<(yt + 255) / 256, 256, 0, stream>>>(y, Yp, yt);
        dim3 grid(M / BN, N / BM);
        hamming_planes_kernel<<<grid, 256, 0, stream>>>(Xp, Yp, out, M);
    } else {
        dim3 grid(M / 64, N / 64);
        hamming_fallback_kernel<<<grid, 256, 0, stream>>>(x, y, out, M);
    }
}

// Round 10
// 106.417 us; speedup vs baseline: 1.1550x; 1.0400x over previous
//
#include <hip/hip_runtime.h>
#include <stdint.h>

// HammingDistance via bit-plane packing.
// Codes 0..7 = 3 bits. Pack bit-plane b of 32 consecutive d's into one u32.
// mismatch(32 elems) = popc((x0^y0)|(x1^y1)|(x2^y2))
// out[n,m] = total_mismatch / 256 (exact, pow2).
//
// R10: occupancy attack. R5's cnt[8][4]+b[8] needs ~110-130 VGPR -> ~3
// waves/SIMD. Split output columns into TWO sequential passes (4 cols each):
// cnt[8][2]=16 regs, b[4]=16 regs -> live ~70-90 VGPR -> LDS-capped 5
// blocks/CU (20 waves/CU). Cost: a re-read per pass (+50% LDS instrs, LDS
// has headroom) + 2x loop overhead. Stores split into two bursts.

#define D_    256
#define GRP   8          // 32-element groups per row
#define RWORD 32         // padded u32 per packed row (8 groups * 4)
#define BM    128
#define BN    128

__global__ __launch_bounds__(256) void pack_planes_kernel(
    const float* __restrict__ in, uint32_t* __restrict__ out, int total)
{
    int idx = blockIdx.x * blockDim.x + threadIdx.x;   // one (row, group) each
    if (idx >= total) return;
    int row = idx >> 3, g = idx & 7;
    const float* p = in + (size_t)row * D_ + g * 32;
    uint32_t b0 = 0, b1 = 0, b2 = 0;
#pragma unroll
    for (int d = 0; d < 32; d += 4) {
        float4 f = *(const float4*)(p + d);
        uint32_t c0 = (uint32_t)f.x, c1 = (uint32_t)f.y;
        uint32_t c2 = (uint32_t)f.z, c3 = (uint32_t)f.w;
        b0 |= ((c0 & 1) << d) | ((c1 & 1) << (d + 1)) |
              ((c2 & 1) << (d + 2)) | ((c3 & 1) << (d + 3));
        b1 |= (((c0 >> 1) & 1) << d) | (((c1 >> 1) & 1) << (d + 1)) |
              (((c2 >> 1) & 1) << (d + 2)) | (((c3 >> 1) & 1) << (d + 3));
        b2 |= (((c0 >> 2) & 1) << d) | (((c1 >> 2) & 1) << (d + 1)) |
              (((c2 >> 2) & 1) << (d + 2)) | (((c3 >> 2) & 1) << (d + 3));
    }
    uint4 v; v.x = b0; v.y = b1; v.z = b2; v.w = 0;
    *(uint4*)&out[(size_t)row * RWORD + g * 4] = v;
}

__global__ __launch_bounds__(256) void hamming_planes_kernel(
    const uint32_t* __restrict__ Xp, const uint32_t* __restrict__ Yp,
    float* __restrict__ out, int Mcols)
{
    // slot = g ^ ((row>>3)&7): b-reads 2-way (free), a-reads broadcast.
    __shared__ __align__(16) uint4 As4[BM * GRP];
    __shared__ __align__(16) uint4 Bs4[BN * GRP];

    const int tid = threadIdx.x;
    const int tn = tid & 15;          // 16 col-threads
    const int tm = tid >> 4;          // 16 row-threads
    const int rowBase = blockIdx.y * BM;
    const int colBase = blockIdx.x * BN;

    // ---- load phase: 1024 uint4 per array, 4 per thread, lane-contiguous ----
    const uint4* Xg = (const uint4*)(Xp + (size_t)rowBase * RWORD);
    const uint4* Yg = (const uint4*)(Yp + (size_t)colBase * RWORD);
#pragma unroll
    for (int i = 0; i < 4; ++i) {
        int f = i * 256 + tid;               // flat (row*8 + g)
        int swz = (f & ~7) | ((f & 7) ^ ((f >> 6) & 7));
        As4[swz] = Xg[f];
        Bs4[swz] = Yg[f];
    }
    __syncthreads();

    const uint4* aBase = As4 + tm * 64;   // rows tm*8..tm*8+7
    const uint4* bBase = Bs4 + tn * 64;   // cols tn*8..tn*8+7
    const float inv = 1.0f / (float)D_;   // out = mismatches / 256

#pragma unroll 1
    for (int pass = 0; pass < 2; ++pass) {
        // this pass: columns tn*8 + 4*pass .. +3
        uint32_t cnt[8][2] = {};

#pragma unroll 1
        for (int g = 0; g < GRP; ++g) {
            const int sa = (g ^ tm) & 7;
            const int sb = (g ^ tn) & 7;
            uint4 b[4];
#pragma unroll
            for (int j = 0; j < 4; ++j)
                b[j] = bBase[(4 * pass + j) * 8 + sb];
#pragma unroll
            for (int i = 0; i < 8; ++i) {
                uint4 a = aBase[i * 8 + sa];
#pragma unroll
                for (int jp = 0; jp < 2; ++jp) {
                    uint32_t ue = (a.x ^ b[2 * jp].x) | (a.y ^ b[2 * jp].y) |
                                  (a.z ^ b[2 * jp].z);
                    uint32_t uo = (a.x ^ b[2 * jp + 1].x) |
                                  (a.y ^ b[2 * jp + 1].y) |
                                  (a.z ^ b[2 * jp + 1].z);
                    cnt[i][jp] += __popc(ue) + (__popc(uo) << 16);
                }
            }
        }

#pragma unroll
        for (int i = 0; i < 8; ++i) {
            float4 r;
            r.x = (float)(cnt[i][0] & 0xffffu) * inv;
            r.y = (float)(cnt[i][0] >> 16) * inv;
            r.z = (float)(cnt[i][1] & 0xffffu) * inv;
            r.w = (float)(cnt[i][1] >> 16) * inv;
            *(float4*)&out[(size_t)(rowBase + tm * 8 + i) * Mcols +
                           colBase + tn * 8 + 4 * pass] = r;
        }
    }
}

// ---------------- fallback (ws too small): fused one-hot kernel ----------------
__device__ __forceinline__ uint32_t pack4_oh(const float* p) {
    float4 f = *(const float4*)p;
    return (1u << (int)f.x) | ((1u << (int)f.y) << 8) |
           ((1u << (int)f.z) << 16) | ((1u << (int)f.w) << 24);
}

__global__ __launch_bounds__(256) void hamming_fallback_kernel(
    const float* __restrict__ X, const float* __restrict__ Y,
    float* __restrict__ out, int Mcols)
{
    __shared__ uint32_t As[16][64];
    __shared__ uint32_t Bs[16][64];
    const int tid = threadIdx.x;
    const int tn = tid & 15, tm = tid >> 4;
    const int rowBase = blockIdx.y * 64, colBase = blockIdx.x * 64;
    const int lrow = tid >> 2, lw4 = (tid & 3) * 4;
    uint32_t cnt[4][4] = {};
    for (int k0 = 0; k0 < 64; k0 += 16) {
        uint4 av, bv;
        const float* px = X + (size_t)(rowBase + lrow) * D_ + (size_t)(k0 + lw4) * 4;
        const float* py = Y + (size_t)(colBase + lrow) * D_ + (size_t)(k0 + lw4) * 4;
        av.x = pack4_oh(px + 0);  av.y = pack4_oh(px + 4);
        av.z = pack4_oh(px + 8);  av.w = pack4_oh(px + 12);
        bv.x = pack4_oh(py + 0);  bv.y = pack4_oh(py + 4);
        bv.z = pack4_oh(py + 8);  bv.w = pack4_oh(py + 12);
        __syncthreads();
        As[lw4 + 0][lrow] = av.x;  As[lw4 + 1][lrow] = av.y;
        As[lw4 + 2][lrow] = av.z;  As[lw4 + 3][lrow] = av.w;
        Bs[lw4 + 0][lrow] = bv.x;  Bs[lw4 + 1][lrow] = bv.y;
        Bs[lw4 + 2][lrow] = bv.z;  Bs[lw4 + 3][lrow] = bv.w;
        __syncthreads();
#pragma unroll
        for (int k = 0; k < 16; ++k) {
            uint4 a4 = *(const uint4*)&As[k][tm * 4];
            uint4 b4 = *(const uint4*)&Bs[k][tn * 4];
            uint32_t a[4] = {a4.x, a4.y, a4.z, a4.w};
            uint32_t b[4] = {b4.x, b4.y, b4.z, b4.w};
#pragma unroll
            for (int i = 0; i < 4; ++i)
#pragma unroll
                for (int j = 0; j < 4; ++j)
                    cnt[i][j] += __popc(a[i] & b[j]);
        }
    }
    const float inv = 1.0f / (float)D_;
#pragma unroll
    for (int i = 0; i < 4; ++i) {
        float4 r;
        r.x = 1.0f - (float)cnt[i][0] * inv;
        r.y = 1.0f - (float)cnt[i][1] * inv;
        r.z = 1.0f - (float)cnt[i][2] * inv;
        r.w = 1.0f - (float)cnt[i][3] * inv;
        *(float4*)&out[(size_t)(rowBase + tm * 4 + i) * Mcols + colBase + tn * 4] = r;
    }
}

extern "C" void kernel_launch(void* const* d_in, const int* in_sizes, int n_in,
                              void* d_out, int out_size, void* d_ws, size_t ws_size,
                              hipStream_t stream) {
    const float* x = (const float*)d_in[0];
    const float* y = (const float*)d_in[1];
    float* out = (float*)d_out;
    const int N = in_sizes[0] / D_;
    const int M = in_sizes[1] / D_;

    const size_t need = ((size_t)N + (size_t)M) * RWORD * sizeof(uint32_t);
    if (ws_size >= need) {
        uint32_t* Xp = (uint32_t*)d_ws;
        uint32_t* Yp = Xp + (size_t)N * RWORD;
        int xt = N * GRP, yt = M * GRP;
        pack_planes_kernel<<<(xt + 255) / 256, 256, 0, stream>>>(x, Xp, xt);
        pack_planes_kernel<<<(yt + 255) / 256, 256, 0, stream>>>(y, Yp, yt);
        dim3 grid(M / BN, N / BM);
        hamming_planes_kernel<<<grid, 256, 0, stream>>>(Xp, Yp, out, M);
    } else {
        dim3 grid(M / 64, N / 64);
        hamming_fallback_kernel<<<grid, 256, 0, stream>>>(x, y, out, M);
    }
}

// Round 11
// 104.083 us; speedup vs baseline: 1.1809x; 1.0224x over previous
//
#include <hip/hip_runtime.h>
#include <stdint.h>

// HammingDistance via bit-plane packing.  == R5 restoration (best: 104.2us) ==
// Codes 0..7 = 3 bits. Pack bit-plane b of 32 consecutive d's into one u32.
// mismatch(32 elems) = popc((x0^y0)|(x1^y1)|(x2^y2))
// out[n,m] = total_mismatch / 256 (exact, pow2).
//
// Probed and closed (R6-R10): asm-pinned accumulate (null), 256x128 tile
// (VGPR cliff), b-double-buffer (VGPR cliff), vec3/b96 reads (negative),
// column pass-split (flat). This configuration is the plateau:
// cnt[8][4] packed-u16 + b[8] + streamed a ~= 110-130 VGPR, 3 waves/SIMD,
// conflict-free-ish LDS (b 2-way, a broadcast), coalesced float4 stores.

#define D_    256
#define GRP   8          // 32-element groups per row
#define RWORD 32         // padded u32 per packed row (8 groups * 4)
#define BM    128
#define BN    128

__global__ __launch_bounds__(256) void pack_planes_kernel(
    const float* __restrict__ in, uint32_t* __restrict__ out, int total)
{
    int idx = blockIdx.x * blockDim.x + threadIdx.x;   // one (row, group) each
    if (idx >= total) return;
    int row = idx >> 3, g = idx & 7;
    const float* p = in + (size_t)row * D_ + g * 32;
    uint32_t b0 = 0, b1 = 0, b2 = 0;
#pragma unroll
    for (int d = 0; d < 32; d += 4) {
        float4 f = *(const float4*)(p + d);
        uint32_t c0 = (uint32_t)f.x, c1 = (uint32_t)f.y;
        uint32_t c2 = (uint32_t)f.z, c3 = (uint32_t)f.w;
        b0 |= ((c0 & 1) << d) | ((c1 & 1) << (d + 1)) |
              ((c2 & 1) << (d + 2)) | ((c3 & 1) << (d + 3));
        b1 |= (((c0 >> 1) & 1) << d) | (((c1 >> 1) & 1) << (d + 1)) |
              (((c2 >> 1) & 1) << (d + 2)) | (((c3 >> 1) & 1) << (d + 3));
        b2 |= (((c0 >> 2) & 1) << d) | (((c1 >> 2) & 1) << (d + 1)) |
              (((c2 >> 2) & 1) << (d + 2)) | (((c3 >> 2) & 1) << (d + 3));
    }
    uint4 v; v.x = b0; v.y = b1; v.z = b2; v.w = 0;
    *(uint4*)&out[(size_t)row * RWORD + g * 4] = v;
}

__global__ __launch_bounds__(256) void hamming_planes_kernel(
    const uint32_t* __restrict__ Xp, const uint32_t* __restrict__ Yp,
    float* __restrict__ out, int Mcols)
{
    // slot = g ^ ((row>>3)&7): b-reads land 2-way (free), a-reads broadcast.
    __shared__ __align__(16) uint4 As4[BM * GRP];
    __shared__ __align__(16) uint4 Bs4[BN * GRP];

    const int tid = threadIdx.x;
    const int tn = tid & 15;          // 16 col-threads
    const int tm = tid >> 4;          // 16 row-threads
    const int rowBase = blockIdx.y * BM;
    const int colBase = blockIdx.x * BN;

    // ---- load phase: 1024 uint4 per array, 4 per thread, lane-contiguous ----
    const uint4* Xg = (const uint4*)(Xp + (size_t)rowBase * RWORD);
    const uint4* Yg = (const uint4*)(Yp + (size_t)colBase * RWORD);
#pragma unroll
    for (int i = 0; i < 4; ++i) {
        int f = i * 256 + tid;               // flat (row*8 + g)
        int swz = (f & ~7) | ((f & 7) ^ ((f >> 6) & 7));
        As4[swz] = Xg[f];
        Bs4[swz] = Yg[f];
    }
    __syncthreads();

    // cnt[i][jp]: low16 = column 2*jp, high16 = column 2*jp+1
    uint32_t cnt[8][4] = {};

#pragma unroll 1
    for (int g = 0; g < GRP; ++g) {
        const int sa = (g ^ tm) & 7;
        const int sb = (g ^ tn) & 7;
        uint4 b[8];
#pragma unroll
        for (int j = 0; j < 8; ++j) b[j] = Bs4[(tn * 8 + j) * 8 + sb];
#pragma unroll
        for (int i = 0; i < 8; ++i) {
            uint4 a = As4[(tm * 8 + i) * 8 + sa];
#pragma unroll
            for (int jp = 0; jp < 4; ++jp) {
                uint32_t ue = (a.x ^ b[2 * jp].x) | (a.y ^ b[2 * jp].y) |
                              (a.z ^ b[2 * jp].z);
                uint32_t uo = (a.x ^ b[2 * jp + 1].x) | (a.y ^ b[2 * jp + 1].y) |
                              (a.z ^ b[2 * jp + 1].z);
                cnt[i][jp] += __popc(ue) + (__popc(uo) << 16);
            }
        }
    }

    const float inv = 1.0f / (float)D_;     // out = mismatches / 256
#pragma unroll
    for (int i = 0; i < 8; ++i) {
        float* orow = &out[(size_t)(rowBase + tm * 8 + i) * Mcols + colBase + tn * 8];
        float4 r0, r1;
        r0.x = (float)(cnt[i][0] & 0xffffu) * inv;
        r0.y = (float)(cnt[i][0] >> 16) * inv;
        r0.z = (float)(cnt[i][1] & 0xffffu) * inv;
        r0.w = (float)(cnt[i][1] >> 16) * inv;
        r1.x = (float)(cnt[i][2] & 0xffffu) * inv;
        r1.y = (float)(cnt[i][2] >> 16) * inv;
        r1.z = (float)(cnt[i][3] & 0xffffu) * inv;
        r1.w = (float)(cnt[i][3] >> 16) * inv;
        *(float4*)(orow + 0) = r0;
        *(float4*)(orow + 4) = r1;
    }
}

// ---------------- fallback (ws too small): fused one-hot kernel ----------------
__device__ __forceinline__ uint32_t pack4_oh(const float* p) {
    float4 f = *(const float4*)p;
    return (1u << (int)f.x) | ((1u << (int)f.y) << 8) |
           ((1u << (int)f.z) << 16) | ((1u << (int)f.w) << 24);
}

__global__ __launch_bounds__(256) void hamming_fallback_kernel(
    const float* __restrict__ X, const float* __restrict__ Y,
    float* __restrict__ out, int Mcols)
{
    __shared__ uint32_t As[16][64];
    __shared__ uint32_t Bs[16][64];
    const int tid = threadIdx.x;
    const int tn = tid & 15, tm = tid >> 4;
    const int rowBase = blockIdx.y * 64, colBase = blockIdx.x * 64;
    const int lrow = tid >> 2, lw4 = (tid & 3) * 4;
    uint32_t cnt[4][4] = {};
    for (int k0 = 0; k0 < 64; k0 += 16) {
        uint4 av, bv;
        const float* px = X + (size_t)(rowBase + lrow) * D_ + (size_t)(k0 + lw4) * 4;
        const float* py = Y + (size_t)(colBase + lrow) * D_ + (size_t)(k0 + lw4) * 4;
        av.x = pack4_oh(px + 0);  av.y = pack4_oh(px + 4);
        av.z = pack4_oh(px + 8);  av.w = pack4_oh(px + 12);
        bv.x = pack4_oh(py + 0);  bv.y = pack4_oh(py + 4);
        bv.z = pack4_oh(py + 8);  bv.w = pack4_oh(py + 12);
        __syncthreads();
        As[lw4 + 0][lrow] = av.x;  As[lw4 + 1][lrow] = av.y;
        As[lw4 + 2][lrow] = av.z;  As[lw4 + 3][lrow] = av.w;
        Bs[lw4 + 0][lrow] = bv.x;  Bs[lw4 + 1][lrow] = bv.y;
        Bs[lw4 + 2][lrow] = bv.z;  Bs[lw4 + 3][lrow] = bv.w;
        __syncthreads();
#pragma unroll
        for (int k = 0; k < 16; ++k) {
            uint4 a4 = *(const uint4*)&As[k][tm * 4];
            uint4 b4 = *(const uint4*)&Bs[k][tn * 4];
            uint32_t a[4] = {a4.x, a4.y, a4.z, a4.w};
            uint32_t b[4] = {b4.x, b4.y, b4.z, b4.w};
#pragma unroll
            for (int i = 0; i < 4; ++i)
#pragma unroll
                for (int j = 0; j < 4; ++j)
                    cnt[i][j] += __popc(a[i] & b[j]);
        }
    }
    const float inv = 1.0f / (float)D_;
#pragma unroll
    for (int i = 0; i < 4; ++i) {
        float4 r;
        r.x = 1.0f - (float)cnt[i][0] * inv;
        r.y = 1.0f - (float)cnt[i][1] * inv;
        r.z = 1.0f - (float)cnt[i][2] * inv;
        r.w = 1.0f - (float)cnt[i][3] * inv;
        *(float4*)&out[(size_t)(rowBase + tm * 4 + i) * Mcols + colBase + tn * 4] = r;
    }
}

extern "C" void kernel_launch(void* const* d_in, const int* in_sizes, int n_in,
                              void* d_out, int out_size, void* d_ws, size_t ws_size,
                              hipStream_t stream) {
    const float* x = (const float*)d_in[0];
    const float* y = (const float*)d_in[1];
    float* out = (float*)d_out;
    const int N = in_sizes[0] / D_;
    const int M = in_sizes[1] / D_;

    const size_t need = ((size_t)N + (size_t)M) * RWORD * sizeof(uint32_t);
    if (ws_size >= need) {
        uint32_t* Xp = (uint32_t*)d_ws;
        uint32_t* Yp = Xp + (size_t)N * RWORD;
        int xt = N * GRP, yt = M * GRP;
        pack_planes_kernel<<<(xt + 255) / 256, 256, 0, stream>>>(x, Xp, xt);
        pack_planes_kernel<<<(yt + 255) / 256, 256, 0, stream>>>(y, Yp, yt);
        dim3 grid(M / BN, N / BM);
        hamming_planes_kernel<<<grid, 256, 0, stream>>>(Xp, Yp, out, M);
    } else {
        dim3 grid(M / 64, N / 64);
        hamming_fallback_kernel<<<grid, 256, 0, stream>>>(x, y, out, M);
    }
}